// Round 12
// baseline (626.754 us; speedup 1.0000x reference)
//
#include <hip/hip_runtime.h>
#include <hip/hip_bf16.h>

typedef unsigned short u16;
typedef unsigned int u32;
typedef unsigned long long u64;
typedef __attribute__((ext_vector_type(8))) short short8;
typedef __attribute__((ext_vector_type(4))) float floatx4;

#define MFMA16(a,b,c) __builtin_amdgcn_mfma_f32_16x16x32_bf16((a),(b),(c),0,0,0)

__device__ __forceinline__ u16 f2bf(float f){
  u32 x = __float_as_uint(f);
  x += 0x7FFFu + ((x >> 16) & 1u);
  return (u16)(x >> 16);
}
__device__ __forceinline__ float bf2f(u16 u){
  return __uint_as_float(((u32)u) << 16);
}
__device__ __forceinline__ float frcp(float x){ return __builtin_amdgcn_rcpf(x); }
__device__ __forceinline__ float fexp2(float x){ return __builtin_amdgcn_exp2f(x); }
// 0.125 * log2(e): scale folded into the exp2 argument
#define KEXP 0.18033688011112042f

// async global->LDS 16B per lane: LDS dest = wave-uniform base + lane*16,
// global src is per-lane (pre-swizzled source pattern).
__device__ __forceinline__ void gl_lds16(const u16* src, u16* dst){
  __builtin_amdgcn_global_load_lds(
      (const __attribute__((address_space(1))) unsigned int*)(u64)(src),
      (__attribute__((address_space(3))) unsigned int*)(u32)(u64)(dst),
      16, 0, 0);
}

// P-buffer swizzle: 16-elem (32B) windows XORed by (row>>2)&3.
__device__ __forceinline__ int p_idx(int row, int col){
  return row * 1024 + (col ^ (((row >> 2) & 3) << 4));
}

// ---------------- weight transpose+convert (all 6): wt[z][j][d] = bf16(w[z][d][j]) ----
__global__ __launch_bounds__(256) void k_wt6(
    const float* __restrict__ w0, const float* __restrict__ w1, const float* __restrict__ w2,
    const float* __restrict__ w3, const float* __restrict__ w4, const float* __restrict__ w5,
    u16* __restrict__ wts)
{
  int z = blockIdx.y;
  const float* w;
  switch (z){ case 0: w = w0; break; case 1: w = w1; break; case 2: w = w2; break;
              case 3: w = w3; break; case 4: w = w4; break; default: w = w5; break; }
  int idx = blockIdx.x * 256 + threadIdx.x;   // 0..262143
  int j = idx >> 9, d = idx & 511;
  wts[(size_t)z * 262144 + idx] = f2bf(w[d * 512 + j]);
}

// ---------------- 5-way projection GEMM: y = x @ w + b, bf16 MFMA ----------------
// z: 0=Q(wq),1=K(wk),2=V(wv, transposed out),3=Q1(wq1),4=K1(wk1)
__global__ __launch_bounds__(256) void k_proj(
    const float* __restrict__ xq, const float* __restrict__ xk, const float* __restrict__ xv,
    const u16* __restrict__ wts,
    const float* __restrict__ bq, const float* __restrict__ bk, const float* __restrict__ bv,
    const float* __restrict__ bq1, const float* __restrict__ bk1,
    u16* __restrict__ Qh, u16* __restrict__ Kh, u16* __restrict__ Vt,
    u16* __restrict__ Q1h, u16* __restrict__ K1h)
{
  __shared__ __align__(16) u16 Xs[64][72];
  __shared__ __align__(16) u16 Wsh[64][72];
  int z = blockIdx.z;
  const float* x; const float* bias; u16* out; int vtm = 0;
  switch (z){
    case 0: x = xq; bias = bq;  out = Qh;  break;
    case 1: x = xk; bias = bk;  out = Kh;  break;
    case 2: x = xv; bias = bv;  out = Vt;  vtm = 1; break;
    case 3: x = xq; bias = bq1; out = Q1h; break;
    default: x = xk; bias = bk1; out = K1h; break;
  }
  const u16* wt = wts + (size_t)z * 262144;
  int tid = threadIdx.x, lane = tid & 63, wid = tid >> 6;
  int wm = wid >> 1, wn = wid & 1;
  int m0 = blockIdx.x * 64, n0 = blockIdx.y * 64;
  int srow = tid >> 2, sc = (tid & 3) * 16;
  int arow = lane & 15, kg = lane >> 4;

  floatx4 acc[2][2];
  #pragma unroll
  for (int i = 0; i < 2; ++i)
    #pragma unroll
    for (int j = 0; j < 2; ++j)
      acc[i][j] = (floatx4){0.f, 0.f, 0.f, 0.f};

  for (int k0 = 0; k0 < 512; k0 += 64){
    const float4* xp = (const float4*)(x + (size_t)(m0 + srow) * 512 + k0 + sc);
    float4 f0 = xp[0], f1 = xp[1], f2 = xp[2], f3 = xp[3];
    short8 v0, v1;
    v0[0] = (short)f2bf(f0.x); v0[1] = (short)f2bf(f0.y); v0[2] = (short)f2bf(f0.z); v0[3] = (short)f2bf(f0.w);
    v0[4] = (short)f2bf(f1.x); v0[5] = (short)f2bf(f1.y); v0[6] = (short)f2bf(f1.z); v0[7] = (short)f2bf(f1.w);
    v1[0] = (short)f2bf(f2.x); v1[1] = (short)f2bf(f2.y); v1[2] = (short)f2bf(f2.z); v1[3] = (short)f2bf(f2.w);
    v1[4] = (short)f2bf(f3.x); v1[5] = (short)f2bf(f3.y); v1[6] = (short)f2bf(f3.z); v1[7] = (short)f2bf(f3.w);
    *(short8*)&Xs[srow][sc]     = v0;
    *(short8*)&Xs[srow][sc + 8] = v1;
    const u16* wp = wt + (size_t)(n0 + srow) * 512 + k0 + sc;
    *(short8*)&Wsh[srow][sc]     = *(const short8*)wp;
    *(short8*)&Wsh[srow][sc + 8] = *(const short8*)(wp + 8);
    __syncthreads();
    #pragma unroll
    for (int kk = 0; kk < 2; ++kk){
      short8 a0 = *(const short8*)&Xs[wm * 32 + arow][kk * 32 + kg * 8];
      short8 a1 = *(const short8*)&Xs[wm * 32 + 16 + arow][kk * 32 + kg * 8];
      short8 b0 = *(const short8*)&Wsh[wn * 32 + arow][kk * 32 + kg * 8];
      short8 b1 = *(const short8*)&Wsh[wn * 32 + 16 + arow][kk * 32 + kg * 8];
      acc[0][0] = MFMA16(a0, b0, acc[0][0]);
      acc[0][1] = MFMA16(a0, b1, acc[0][1]);
      acc[1][0] = MFMA16(a1, b0, acc[1][0]);
      acc[1][1] = MFMA16(a1, b1, acc[1][1]);
    }
    __syncthreads();
  }
  #pragma unroll
  for (int mm = 0; mm < 2; ++mm)
    #pragma unroll
    for (int nn = 0; nn < 2; ++nn){
      int j = n0 + wn * 32 + nn * 16 + arow;
      int h = j >> 6, dh = j & 63;
      float bval = bias[j];
      #pragma unroll
      for (int i = 0; i < 4; ++i){
        int sg = m0 + wm * 32 + mm * 16 + kg * 4 + i;
        int bb = sg >> 10, s = sg & 1023;
        float val = acc[mm][nn][i] + bval;
        size_t o = vtm ? (((size_t)((bb << 3) + h) * 64 + dh) * 1024 + s)
                       : (((size_t)((bb << 3) + h) * 1024 + s) * 64 + dh);
        out[o] = f2bf(val);
      }
    }
}

// ---------------- fused dual-QK attention + r_att + PV --------------------------------
// TLP redesign: 512 threads (8 waves), 32 q-rows/block, 80 KB LDS -> TWO independent
// blocks per CU at uncorrelated phases. When one block waits on DMA/barrier, the
// other's waves issue MFMA/VALU (m114 co-scheduling) — the latency hiding that
// intra-block pipelining (R7-R11, all <= R6) could not provide, because a single
// 16-wave block stalls the whole CU at every barrier.
// Grid dim3(16,32): blockIdx.x=b fastest -> batch b's 32 blocks all on XCD b%8
// (K1/K working set 2 batches x 2 MB ~ L2). Simple __syncthreads sync (R6-proven).
__global__ void __launch_bounds__(512)
__attribute__((amdgpu_waves_per_eu(4, 4)))
k_attn(
    const u16* __restrict__ Qh, const u16* __restrict__ Kh, const u16* __restrict__ Vt,
    const u16* __restrict__ Q1h, const u16* __restrict__ K1h,
    const int* __restrict__ mask, u16* __restrict__ xa, float* __restrict__ ratt)
{
  extern __shared__ __align__(16) char smem[];
  u16* P   = (u16*)smem;                          // [32][1024] bf16, swizzled (64 KB)
  u16* stg = (u16*)(smem + 65536);                // 16 KB single staging buffer
  float* ssum = (float*)(smem + 65536);           // [32][4] (aliased; used post-QK)
  float* rls  = (float*)(smem + 65536 + 512);     // [32]

  const int tid = threadIdx.x, lane = tid & 63, wid = tid >> 6;
  const int arow = lane & 15, kg = lane >> 4;
  const int b = blockIdx.x, qt = blockIdx.y;
  const int r0 = (wid & 1) * 16;     // q-row strip (2 strips x 16 = 32 rows)
  const int cg = wid >> 1;           // col group (4 groups x 16 = 64 cols / dh)
  const int cres = cg * 16 + arow;   // k-col / dh residue (mod 64)
  const int wrow = wid * 4;          // rows owned in normalize (8 waves x 4 = 32)

  // QK staging map (per 8 KB half): thread sources 16B; dst linear = tid*16B
  const int ls_r = tid >> 3;                    // tile row (k-col) 0..63
  const int ls_c = (tid & 7) ^ (ls_r & 7);      // swizzled source chunk
  // PV staging map (16 KB tile [64 dh][128 k]): two issues q=0,1; idx = q*512+tid
  const int pv_r0 = tid >> 4,           pv_c0 = (tid & 15) ^ (pv_r0 & 7);
  const int pv_r1 = (tid + 512) >> 4,   pv_c1 = ((tid + 512) & 15) ^ (pv_r1 & 7);
  // per-wave linear LDS staging base (u16): tid*8 = wid*512 + lane*8
  u16* const sbase = stg + wid * 512;

  u32 mb = 0;
  #pragma unroll
  for (int t = 0; t < 16; ++t)
    mb |= (mask[b * 1024 + t * 64 + cres] != 0 ? 1u : 0u) << t;

  float racc[4][16];
  #pragma unroll
  for (int r = 0; r < 4; ++r)
    #pragma unroll
    for (int j = 0; j < 16; ++j) racc[r][j] = 0.f;

  for (int h = 0; h < 8; ++h){
    const size_t hb = (size_t)(b * 8 + h);
    const u16* qp  = Qh  + (hb * 1024 + qt * 32 + r0 + arow) * 64 + kg * 8;
    const u16* q1p = Q1h + (hb * 1024 + qt * 32 + r0 + arow) * 64 + kg * 8;
    short8 aq0 = *(const short8*)qp,  aq1 = *(const short8*)(qp + 32);
    short8 ap0 = *(const short8*)q1p, ap1 = *(const short8*)(q1p + 32);

    const u16* k1s = K1h + hb * 65536 + (size_t)ls_r * 64 + ls_c * 8;
    const u16* ks  = Kh  + hb * 65536 + (size_t)ls_r * 64 + ls_c * 8;

    // ---- QK phase: 16 tiles of 64 k-cols; single-buffered staging ----
    float sacc[4] = {0.f, 0.f, 0.f, 0.f};
    for (int t = 0; t < 16; ++t){
      gl_lds16(k1s + (size_t)t * 4096, sbase);           // K1 half -> [0,8KB)
      gl_lds16(ks  + (size_t)t * 4096, sbase + 4096);    // K  half -> [8KB,16KB)
      __syncthreads();
      const int swl = (cres & 7) * 8;
      short8 b1a = *(const short8*)&stg[cres * 64 + ((     kg * 8) ^ swl)];
      short8 b1b = *(const short8*)&stg[cres * 64 + ((32 + kg * 8) ^ swl)];
      short8 bea = *(const short8*)&stg[4096 + cres * 64 + ((     kg * 8) ^ swl)];
      short8 beb = *(const short8*)&stg[4096 + cres * 64 + ((32 + kg * 8) ^ swl)];
      floatx4 cg4 = (floatx4){0.f, 0.f, 0.f, 0.f};
      floatx4 ce4 = (floatx4){0.f, 0.f, 0.f, 0.f};
      cg4 = MFMA16(ap0, b1a, cg4); cg4 = MFMA16(ap1, b1b, cg4);
      ce4 = MFMA16(aq0, bea, ce4); ce4 = MFMA16(aq1, beb, ce4);
      const float msk = ((mb >> t) & 1u) ? 1.0f : 0.0f;
      #pragma unroll
      for (int i = 0; i < 4; ++i){
        float p = fexp2(ce4[i] * KEXP) * msk;
        float g = frcp(1.0f + fexp2(-cg4[i] * KEXP));
        sacc[i] += p;
        P[p_idx(r0 + kg * 4 + i, t * 64 + cres)] = f2bf(p * g);
      }
      __syncthreads();   // staged reads done; buffer free for next tile
    }

    // ---- row-sum reduce -> ssum (staging buffer now dead) ----
    #pragma unroll
    for (int i = 0; i < 4; ++i){
      #pragma unroll
      for (int off = 1; off <= 8; off <<= 1)
        sacc[i] += __shfl_xor(sacc[i], off, 64);
    }
    if (arow == 0){
      #pragma unroll
      for (int i = 0; i < 4; ++i)
        ssum[(r0 + kg * 4 + i) * 4 + cg] = sacc[i];
    }
    __syncthreads();   // #1: all P writes + ssum ready

    // ---- normalize: accumulate r_att (1/sum folded); P keeps unnormalized u ----
    #pragma unroll
    for (int r = 0; r < 4; ++r){
      const int row = wrow + r;
      float s = ssum[row * 4 + 0] + ssum[row * 4 + 1] + ssum[row * 4 + 2] + ssum[row * 4 + 3];
      float rl = frcp(s);
      if (lane == 0) rls[row] = rl;
      float rlh = rl * 0.125f;
      #pragma unroll
      for (int j = 0; j < 8; ++j){
        u32 w = *(const u32*)&P[p_idx(row, j * 128 + lane * 2)];
        float lo = __uint_as_float(w << 16);
        float hi = __uint_as_float(w & 0xFFFF0000u);
        racc[r][2 * j]     += lo * rlh;
        racc[r][2 * j + 1] += hi * rlh;
      }
    }
    __syncthreads();   // #2: rls ready
    float rlv[4];
    #pragma unroll
    for (int i = 0; i < 4; ++i) rlv[i] = rls[r0 + kg * 4 + i];
    __syncthreads();   // #2b: rls consumed before V staging overwrites this region

    // ---- PV phase: 8 tiles of 128 k; V tile [64 dh][128 k] staged in 2 issues ----
    const u16* vs0 = Vt + hb * 65536 + (size_t)pv_r0 * 1024 + pv_c0 * 8;
    const u16* vs1 = Vt + hb * 65536 + (size_t)pv_r1 * 1024 + pv_c1 * 8;
    floatx4 cpv = (floatx4){0.f, 0.f, 0.f, 0.f};
    for (int t = 0; t < 8; ++t){
      gl_lds16(vs0 + (size_t)t * 128, sbase);            // rows 0..31 region
      gl_lds16(vs1 + (size_t)t * 128, sbase + 4096);     // rows 32..63 region
      __syncthreads();
      const int swv = (cres & 7) * 8;
      #pragma unroll
      for (int ks2 = 0; ks2 < 4; ++ks2){
        short8 a  = *(const short8*)&P[p_idx(r0 + arow, t * 128 + ks2 * 32 + kg * 8)];
        short8 bv = *(const short8*)&stg[cres * 128 + ((ks2 * 32 + kg * 8) ^ swv)];
        cpv = MFMA16(a, bv, cpv);
      }
      __syncthreads();
    }
    // ---- epilogue: scale by 1/sum, write xa ----
    #pragma unroll
    for (int i = 0; i < 4; ++i)
      xa[((size_t)(b * 1024 + qt * 32 + r0 + kg * 4 + i)) * 512 + h * 64 + cres] =
          f2bf(cpv[i] * rlv[i]);
    __syncthreads();   // #3: all P reads done before next head's P writes
  }

  // ---- r_att writeout (f32, float2-coalesced: col = j*128 + lane*2 + par) ----
  #pragma unroll
  for (int r = 0; r < 4; ++r){
    const size_t rb = ((size_t)(b * 1024 + qt * 32 + wrow + r)) * 1024;
    #pragma unroll
    for (int j = 0; j < 8; ++j){
      float2 v = {racc[r][2 * j], racc[r][2 * j + 1]};
      *(float2*)&ratt[rb + j * 128 + lane * 2] = v;
    }
  }
}

// ---------------- final FC: out = xa @ wfc + bfc (f32 out) ----------------
__global__ __launch_bounds__(256) void k_fc(
    const u16* __restrict__ xa, const u16* __restrict__ wt,
    const float* __restrict__ bias, float* __restrict__ out)
{
  __shared__ __align__(16) u16 Xs[64][72];
  __shared__ __align__(16) u16 Wsh[64][72];
  int tid = threadIdx.x, lane = tid & 63, wid = tid >> 6;
  int wm = wid >> 1, wn = wid & 1;
  int m0 = blockIdx.x * 64, n0 = blockIdx.y * 64;
  int srow = tid >> 2, sc = (tid & 3) * 16;
  int arow = lane & 15, kg = lane >> 4;

  floatx4 acc[2][2];
  #pragma unroll
  for (int i = 0; i < 2; ++i)
    #pragma unroll
    for (int j = 0; j < 2; ++j)
      acc[i][j] = (floatx4){0.f, 0.f, 0.f, 0.f};

  for (int k0 = 0; k0 < 512; k0 += 64){
    const u16* xp = xa + (size_t)(m0 + srow) * 512 + k0 + sc;
    *(short8*)&Xs[srow][sc]     = *(const short8*)xp;
    *(short8*)&Xs[srow][sc + 8] = *(const short8*)(xp + 8);
    const u16* wp = wt + (size_t)(n0 + srow) * 512 + k0 + sc;
    *(short8*)&Wsh[srow][sc]     = *(const short8*)wp;
    *(short8*)&Wsh[srow][sc + 8] = *(const short8*)(wp + 8);
    __syncthreads();
    #pragma unroll
    for (int kk = 0; kk < 2; ++kk){
      short8 a0 = *(const short8*)&Xs[wm * 32 + arow][kk * 32 + kg * 8];
      short8 a1 = *(const short8*)&Xs[wm * 32 + 16 + arow][kk * 32 + kg * 8];
      short8 b0 = *(const short8*)&Wsh[wn * 32 + arow][kk * 32 + kg * 8];
      short8 b1 = *(const short8*)&Wsh[wn * 32 + 16 + arow][kk * 32 + kg * 8];
      acc[0][0] = MFMA16(a0, b0, acc[0][0]);
      acc[0][1] = MFMA16(a0, b1, acc[0][1]);
      acc[1][0] = MFMA16(a1, b0, acc[1][0]);
      acc[1][1] = MFMA16(a1, b1, acc[1][1]);
    }
    __syncthreads();
  }
  #pragma unroll
  for (int mm = 0; mm < 2; ++mm)
    #pragma unroll
    for (int nn = 0; nn < 2; ++nn){
      int j = n0 + wn * 32 + nn * 16 + arow;
      float bval = bias[j];
      #pragma unroll
      for (int i = 0; i < 4; ++i){
        int sg = m0 + wm * 32 + mm * 16 + kg * 4 + i;
        out[(size_t)sg * 512 + j] = acc[mm][nn][i] + bval;
      }
    }
}

extern "C" void kernel_launch(void* const* d_in, const int* in_sizes, int n_in,
                              void* d_out, int out_size, void* d_ws, size_t ws_size,
                              hipStream_t stream)
{
  const float* query = (const float*)d_in[0];
  const float* key   = (const float*)d_in[1];
  const float* value = (const float*)d_in[2];
  const int*   mask  = (const int*)d_in[3];
  const float* wq  = (const float*)d_in[4];  const float* bq  = (const float*)d_in[5];
  const float* wk  = (const float*)d_in[6];  const float* bk  = (const float*)d_in[7];
  const float* wv  = (const float*)d_in[8];  const float* bv  = (const float*)d_in[9];
  const float* wq1 = (const float*)d_in[10]; const float* bq1 = (const float*)d_in[11];
  const float* wk1 = (const float*)d_in[12]; const float* bk1 = (const float*)d_in[13];
  const float* wfc = (const float*)d_in[14]; const float* bfc = (const float*)d_in[15];

  u16* ws  = (u16*)d_ws;
  u16* Qh  = ws;
  u16* Kh  = Qh  + 8388608;
  u16* Vt  = Kh  + 8388608;
  u16* Q1h = Vt  + 8388608;
  u16* K1h = Q1h + 8388608;
  u16* xa  = K1h + 8388608;
  u16* wts = xa  + 8388608;   // 6 * 262144 bf16

  float* outx = (float*)d_out;
  float* ratt = outx + 8388608;

  (void)hipFuncSetAttribute((const void*)k_attn,
                            hipFuncAttributeMaxDynamicSharedMemorySize, 81920);

  k_wt6<<<dim3(1024, 6), dim3(256), 0, stream>>>(wq, wk, wv, wq1, wk1, wfc, wts);

  k_proj<<<dim3(256, 8, 5), dim3(256), 0, stream>>>(
      query, key, value, wts, bq, bk, bv, bq1, bk1, Qh, Kh, Vt, Q1h, K1h);

  k_attn<<<dim3(16, 32), dim3(512), 81920, stream>>>(
      Qh, Kh, Vt, Q1h, K1h, mask, xa, ratt);

  k_fc<<<dim3(256, 8), dim3(256), 0, stream>>>(
      xa, wts + 5 * 262144, bfc, outx);
}

// Round 14
// 500.957 us; speedup vs baseline: 1.2511x; 1.2511x over previous
//
#include <hip/hip_runtime.h>
#include <hip/hip_bf16.h>

typedef unsigned short u16;
typedef unsigned int u32;
typedef unsigned long long u64;
typedef __attribute__((ext_vector_type(8))) short short8;
typedef __attribute__((ext_vector_type(4))) float floatx4;

#define MFMA16(a,b,c) __builtin_amdgcn_mfma_f32_16x16x32_bf16((a),(b),(c),0,0,0)

__device__ __forceinline__ u16 f2bf(float f){
  u32 x = __float_as_uint(f);
  x += 0x7FFFu + ((x >> 16) & 1u);
  return (u16)(x >> 16);
}
__device__ __forceinline__ float frcp(float x){ return __builtin_amdgcn_rcpf(x); }
__device__ __forceinline__ float fexp2(float x){ return __builtin_amdgcn_exp2f(x); }
// 0.125 * log2(e): scale folded into the exp2 argument
#define KEXP 0.18033688011112042f
#define Z4 ((floatx4){0.f,0.f,0.f,0.f})

// async global->LDS 16B per lane: LDS dest = wave-uniform base + lane*16,
// global src is per-lane (pre-swizzled source pattern).
__device__ __forceinline__ void gl_lds16(const u16* src, u16* dst){
  __builtin_amdgcn_global_load_lds(
      (const __attribute__((address_space(1))) unsigned int*)(u64)(src),
      (__attribute__((address_space(3))) unsigned int*)(u32)(u64)(dst),
      16, 0, 0);
}

// P-buffer swizzle: 16-elem (32B) windows XORed by (row>>2)&3.
__device__ __forceinline__ int p_idx(int row, int col){
  return row * 1024 + (col ^ (((row >> 2) & 3) << 4));
}

// ---------------- weight transpose+convert (all 6): wt[z][j][d] = bf16(w[z][d][j]) ----
__global__ __launch_bounds__(256) void k_wt6(
    const float* __restrict__ w0, const float* __restrict__ w1, const float* __restrict__ w2,
    const float* __restrict__ w3, const float* __restrict__ w4, const float* __restrict__ w5,
    u16* __restrict__ wts)
{
  int z = blockIdx.y;
  const float* w;
  switch (z){ case 0: w = w0; break; case 1: w = w1; break; case 2: w = w2; break;
              case 3: w = w3; break; case 4: w = w4; break; default: w = w5; break; }
  int idx = blockIdx.x * 256 + threadIdx.x;
  int j = idx >> 9, d = idx & 511;
  wts[(size_t)z * 262144 + idx] = f2bf(w[d * 512 + j]);
}

// ---------------- 5-way projection GEMM, 128x128 tile ----------------
// z: 0=Q,1=K,2=V(transposed out),3=Q1,4=K1. 256 thr / 4 waves (2x2), each wave
// 64x64 out = 4x4 frags. B (bf16 weights) via global_load_lds: linear LDS dest +
// XOR-swizzled source; reads use matching XOR (k_attn-proven pattern). A (f32 input)
// reg-staged f32->bf16 into +8-padded LDS (pad -> 2-way conflicts = free, m136).
__global__ __launch_bounds__(256) void k_proj(
    const float* __restrict__ xq, const float* __restrict__ xk, const float* __restrict__ xv,
    const u16* __restrict__ wts,
    const float* __restrict__ bq, const float* __restrict__ bk, const float* __restrict__ bv,
    const float* __restrict__ bq1, const float* __restrict__ bk1,
    u16* __restrict__ Qh, u16* __restrict__ Kh, u16* __restrict__ Vt,
    u16* __restrict__ Q1h, u16* __restrict__ K1h)
{
  __shared__ __align__(16) u16 As[128][72];    // padded
  __shared__ __align__(16) u16 Bs[128 * 64];   // linear, swizzled
  int z = blockIdx.z;
  const float* x; const float* bias; u16* out; int vtm = 0;
  switch (z){
    case 0: x = xq; bias = bq;  out = Qh;  break;
    case 1: x = xk; bias = bk;  out = Kh;  break;
    case 2: x = xv; bias = bv;  out = Vt;  vtm = 1; break;
    case 3: x = xq; bias = bq1; out = Q1h; break;
    default: x = xk; bias = bk1; out = K1h; break;
  }
  const u16* wt = wts + (size_t)z * 262144;
  const int tid = threadIdx.x, lane = tid & 63, wid = tid >> 6;
  const int wm = wid >> 1, wn = wid & 1;
  const int m0 = blockIdx.x * 128, n0 = blockIdx.y * 128;
  const int arow = lane & 15, kg = lane >> 4;
  // A staging: thread -> (row ar, 32-col half ah)
  const int ar = tid >> 1, ah = (tid & 1) * 32;
  // B staging via gl_lds16: per issue q, row = q*32 + br, src chunk = bc ^ (br&7)
  const int br = tid >> 3, bc = tid & 7;
  u16* const bdst = Bs + wid * 512;           // + q*2048

  floatx4 acc[4][4];
  #pragma unroll
  for (int i = 0; i < 4; ++i)
    #pragma unroll
    for (int j = 0; j < 4; ++j) acc[i][j] = Z4;

  for (int k0 = 0; k0 < 512; k0 += 64){
    // ---- B tile: 4 async issues (16 KB) ----
    #pragma unroll
    for (int q = 0; q < 4; ++q)
      gl_lds16(wt + (size_t)(n0 + q * 32 + br) * 512 + k0 + ((bc ^ (br & 7)) * 8),
               bdst + q * 2048);
    // ---- A tile: f32 -> bf16 reg-staged (32 f32/thread) ----
    const float4* xp = (const float4*)(x + (size_t)(m0 + ar) * 512 + k0 + ah);
    #pragma unroll
    for (int j = 0; j < 4; ++j){
      float4 f0 = xp[2 * j], f1 = xp[2 * j + 1];
      short8 v;
      v[0] = (short)f2bf(f0.x); v[1] = (short)f2bf(f0.y);
      v[2] = (short)f2bf(f0.z); v[3] = (short)f2bf(f0.w);
      v[4] = (short)f2bf(f1.x); v[5] = (short)f2bf(f1.y);
      v[6] = (short)f2bf(f1.z); v[7] = (short)f2bf(f1.w);
      *(short8*)&As[ar][ah + j * 8] = v;
    }
    __syncthreads();
    #pragma unroll
    for (int kk = 0; kk < 2; ++kk){
      short8 af[4], bf[4];
      #pragma unroll
      for (int mm = 0; mm < 4; ++mm)
        af[mm] = *(const short8*)&As[wm * 64 + mm * 16 + arow][kk * 32 + kg * 8];
      #pragma unroll
      for (int nn = 0; nn < 4; ++nn){
        int rr = wn * 64 + nn * 16 + arow;
        bf[nn] = *(const short8*)&Bs[rr * 64 + ((kk * 32 + kg * 8) ^ ((rr & 7) * 8))];
      }
      #pragma unroll
      for (int mm = 0; mm < 4; ++mm)
        #pragma unroll
        for (int nn = 0; nn < 4; ++nn)
          acc[mm][nn] = MFMA16(af[mm], bf[nn], acc[mm][nn]);
    }
    __syncthreads();
  }
  #pragma unroll
  for (int mm = 0; mm < 4; ++mm)
    #pragma unroll
    for (int nn = 0; nn < 4; ++nn){
      int j = n0 + wn * 64 + nn * 16 + arow;
      int h = j >> 6, dh = j & 63;
      float bval = bias[j];
      #pragma unroll
      for (int i = 0; i < 4; ++i){
        int sg = m0 + wm * 64 + mm * 16 + kg * 4 + i;
        int bb = sg >> 10, s = sg & 1023;
        float val = acc[mm][nn][i] + bval;
        size_t o = vtm ? (((size_t)((bb << 3) + h) * 64 + dh) * 1024 + s)
                       : (((size_t)((bb << 3) + h) * 1024 + s) * 64 + dh);
        out[o] = f2bf(val);
      }
    }
}

// ---------------- fused dual-QK attention + r_att + PV (R6-proven, 368 us) -----------
__global__ void __launch_bounds__(1024)
__attribute__((amdgpu_waves_per_eu(4, 4)))
k_attn(
    const u16* __restrict__ Qh, const u16* __restrict__ Kh, const u16* __restrict__ Vt,
    const u16* __restrict__ Q1h, const u16* __restrict__ K1h,
    const int* __restrict__ mask, u16* __restrict__ xa, float* __restrict__ ratt)
{
  extern __shared__ __align__(16) char smem[];
  u16* P   = (u16*)smem;                          // [64][1024] bf16, swizzled
  u16* stg = (u16*)(smem + 131072);               // 32 KB: 2 x 16 KB buffers
  float* ssum = (float*)(smem + 131072);          // [64][4] (aliased over stage buf0)
  float* rls  = (float*)(smem + 131072 + 1024);   // [64]

  const int tid = threadIdx.x, lane = tid & 63, wid = tid >> 6;
  const int arow = lane & 15, kg = lane >> 4;
  const int b = blockIdx.x, qt = blockIdx.y;
  const int r0 = (wid & 3) * 16;
  const int c0 = (wid >> 2) * 16;
  const int cres = c0 + arow;
  const int wrow = wid * 4;

  const int ls_half = tid >> 9;
  const int ls_r = (tid & 511) >> 3;
  const int ls_c = (tid & 7) ^ (ls_r & 7);
  const int pv_r = tid >> 4;
  const int pv_c = (tid & 15) ^ (pv_r & 7);
  u16* const sbase = stg + wid * 512;

  u32 mb = 0;
  #pragma unroll
  for (int t = 0; t < 16; ++t)
    mb |= (mask[b * 1024 + t * 64 + cres] != 0 ? 1u : 0u) << t;

  float racc[4][16];
  #pragma unroll
  for (int r = 0; r < 4; ++r)
    #pragma unroll
    for (int j = 0; j < 16; ++j) racc[r][j] = 0.f;

  for (int h = 0; h < 8; ++h){
    const size_t hb = (size_t)(b * 8 + h);
    const u16* qp  = Qh  + (hb * 1024 + qt * 64 + r0 + arow) * 64 + kg * 8;
    const u16* q1p = Q1h + (hb * 1024 + qt * 64 + r0 + arow) * 64 + kg * 8;
    short8 aq0 = *(const short8*)qp,  aq1 = *(const short8*)(qp + 32);
    short8 ap0 = *(const short8*)q1p, ap1 = *(const short8*)(q1p + 32);

    const u16* lsrc = (ls_half ? Kh : K1h) + hb * 65536 + (size_t)ls_r * 64 + ls_c * 8;

    gl_lds16(lsrc, sbase);
    __syncthreads();

    float sacc[4] = {0.f, 0.f, 0.f, 0.f};
    for (int t = 0; t < 16; ++t){
      if (t < 15)
        gl_lds16(lsrc + (size_t)(t + 1) * 4096, sbase + (((t + 1) & 1) << 13));
      const u16* kb = stg + ((t & 1) << 13);
      const int swl = (cres & 7) * 8;
      short8 b1a = *(const short8*)&kb[cres * 64 + ((     kg * 8) ^ swl)];
      short8 b1b = *(const short8*)&kb[cres * 64 + ((32 + kg * 8) ^ swl)];
      short8 bea = *(const short8*)&kb[4096 + cres * 64 + ((     kg * 8) ^ swl)];
      short8 beb = *(const short8*)&kb[4096 + cres * 64 + ((32 + kg * 8) ^ swl)];
      floatx4 cg = Z4;
      floatx4 ce = Z4;
      cg = MFMA16(ap0, b1a, cg); cg = MFMA16(ap1, b1b, cg);
      ce = MFMA16(aq0, bea, ce); ce = MFMA16(aq1, beb, ce);
      const float msk = ((mb >> t) & 1u) ? 1.0f : 0.0f;
      #pragma unroll
      for (int i = 0; i < 4; ++i){
        float p = fexp2(ce[i] * KEXP) * msk;
        float g = frcp(1.0f + fexp2(-cg[i] * KEXP));
        sacc[i] += p;
        P[p_idx(r0 + kg * 4 + i, t * 64 + cres)] = f2bf(p * g);
      }
      __syncthreads();
    }

    #pragma unroll
    for (int i = 0; i < 4; ++i){
      #pragma unroll
      for (int off = 1; off <= 8; off <<= 1)
        sacc[i] += __shfl_xor(sacc[i], off, 64);
    }
    if (arow == 0){
      #pragma unroll
      for (int i = 0; i < 4; ++i)
        ssum[(r0 + kg * 4 + i) * 4 + (wid >> 2)] = sacc[i];
    }
    __syncthreads();

    #pragma unroll
    for (int r = 0; r < 4; ++r){
      const int row = wrow + r;
      float s = ssum[row * 4 + 0] + ssum[row * 4 + 1] + ssum[row * 4 + 2] + ssum[row * 4 + 3];
      float rl = frcp(s);
      if (lane == 0) rls[row] = rl;
      short8 u0 = *(const short8*)&P[p_idx(row, lane * 16)];
      short8 u1 = *(const short8*)&P[p_idx(row, lane * 16 + 8)];
      float rlh = rl * 0.125f;
      #pragma unroll
      for (int j = 0; j < 8; ++j){
        racc[r][j]     += __uint_as_float(((u32)(u16)u0[j]) << 16) * rlh;
        racc[r][8 + j] += __uint_as_float(((u32)(u16)u1[j]) << 16) * rlh;
      }
    }
    __syncthreads();
    float rlv[4];
    #pragma unroll
    for (int i = 0; i < 4; ++i) rlv[i] = rls[r0 + kg * 4 + i];
    __syncthreads();

    const u16* vsrc = Vt + hb * 65536 + (size_t)pv_r * 1024 + pv_c * 8;
    gl_lds16(vsrc, sbase);
    __syncthreads();

    floatx4 cpv = Z4;
    for (int t = 0; t < 8; ++t){
      if (t < 7)
        gl_lds16(vsrc + (size_t)(t + 1) * 128, sbase + (((t + 1) & 1) << 13));
      const u16* vb = stg + ((t & 1) << 13);
      const int swv = (cres & 7) * 8;
      #pragma unroll
      for (int ks = 0; ks < 4; ++ks){
        short8 a  = *(const short8*)&P[p_idx(r0 + arow, t * 128 + ks * 32 + kg * 8)];
        short8 bv = *(const short8*)&vb[cres * 128 + ((ks * 32 + kg * 8) ^ swv)];
        cpv = MFMA16(a, bv, cpv);
      }
      __syncthreads();
    }
    #pragma unroll
    for (int i = 0; i < 4; ++i)
      xa[((size_t)(b * 1024 + qt * 64 + r0 + kg * 4 + i)) * 512 + h * 64 + cres] =
          f2bf(cpv[i] * rlv[i]);
  }

  #pragma unroll
  for (int r = 0; r < 4; ++r){
    const size_t rb = ((size_t)(b * 1024 + qt * 64 + wrow + r)) * 1024 + lane * 16;
    #pragma unroll
    for (int q = 0; q < 4; ++q){
      float4 v = {racc[r][q * 4 + 0], racc[r][q * 4 + 1], racc[r][q * 4 + 2], racc[r][q * 4 + 3]};
      *(float4*)&ratt[rb + q * 4] = v;
    }
  }
}

// ---------------- final FC, 128x128 tile: out = xa @ wfc + bfc (f32 out) -------------
// Both operands bf16 -> both staged via global_load_lds (linear + XOR-swizzled src).
__global__ __launch_bounds__(256) void k_fc(
    const u16* __restrict__ xa, const u16* __restrict__ wt,
    const float* __restrict__ bias, float* __restrict__ out)
{
  __shared__ __align__(16) u16 Asf[128 * 64];
  __shared__ __align__(16) u16 Bsf[128 * 64];
  const int tid = threadIdx.x, lane = tid & 63, wid = tid >> 6;
  const int wm = wid >> 1, wn = wid & 1;
  const int m0 = blockIdx.x * 128, n0 = blockIdx.y * 128;
  const int arow = lane & 15, kg = lane >> 4;
  const int br = tid >> 3, bc = tid & 7;
  u16* const adst = Asf + wid * 512;
  u16* const bdst = Bsf + wid * 512;

  floatx4 acc[4][4];
  #pragma unroll
  for (int i = 0; i < 4; ++i)
    #pragma unroll
    for (int j = 0; j < 4; ++j) acc[i][j] = Z4;

  for (int k0 = 0; k0 < 512; k0 += 64){
    #pragma unroll
    for (int q = 0; q < 4; ++q){
      gl_lds16(xa + (size_t)(m0 + q * 32 + br) * 512 + k0 + ((bc ^ (br & 7)) * 8),
               adst + q * 2048);
      gl_lds16(wt + (size_t)(n0 + q * 32 + br) * 512 + k0 + ((bc ^ (br & 7)) * 8),
               bdst + q * 2048);
    }
    __syncthreads();
    #pragma unroll
    for (int kk = 0; kk < 2; ++kk){
      short8 af[4], bf[4];
      #pragma unroll
      for (int mm = 0; mm < 4; ++mm){
        int rr = wm * 64 + mm * 16 + arow;
        af[mm] = *(const short8*)&Asf[rr * 64 + ((kk * 32 + kg * 8) ^ ((rr & 7) * 8))];
      }
      #pragma unroll
      for (int nn = 0; nn < 4; ++nn){
        int rr = wn * 64 + nn * 16 + arow;
        bf[nn] = *(const short8*)&Bsf[rr * 64 + ((kk * 32 + kg * 8) ^ ((rr & 7) * 8))];
      }
      #pragma unroll
      for (int mm = 0; mm < 4; ++mm)
        #pragma unroll
        for (int nn = 0; nn < 4; ++nn)
          acc[mm][nn] = MFMA16(af[mm], bf[nn], acc[mm][nn]);
    }
    __syncthreads();
  }
  #pragma unroll
  for (int mm = 0; mm < 4; ++mm)
    #pragma unroll
    for (int nn = 0; nn < 4; ++nn){
      int j = n0 + wn * 64 + nn * 16 + arow;
      float bval = bias[j];
      #pragma unroll
      for (int i = 0; i < 4; ++i){
        int sg = m0 + wm * 64 + mm * 16 + kg * 4 + i;
        out[(size_t)sg * 512 + j] = acc[mm][nn][i] + bval;
      }
    }
}

extern "C" void kernel_launch(void* const* d_in, const int* in_sizes, int n_in,
                              void* d_out, int out_size, void* d_ws, size_t ws_size,
                              hipStream_t stream)
{
  const float* query = (const float*)d_in[0];
  const float* key   = (const float*)d_in[1];
  const float* value = (const float*)d_in[2];
  const int*   mask  = (const int*)d_in[3];
  const float* wq  = (const float*)d_in[4];  const float* bq  = (const float*)d_in[5];
  const float* wk  = (const float*)d_in[6];  const float* bk  = (const float*)d_in[7];
  const float* wv  = (const float*)d_in[8];  const float* bv  = (const float*)d_in[9];
  const float* wq1 = (const float*)d_in[10]; const float* bq1 = (const float*)d_in[11];
  const float* wk1 = (const float*)d_in[12]; const float* bk1 = (const float*)d_in[13];
  const float* wfc = (const float*)d_in[14]; const float* bfc = (const float*)d_in[15];

  u16* ws  = (u16*)d_ws;
  u16* Qh  = ws;
  u16* Kh  = Qh  + 8388608;
  u16* Vt  = Kh  + 8388608;
  u16* Q1h = Vt  + 8388608;
  u16* K1h = Q1h + 8388608;
  u16* xa  = K1h + 8388608;
  u16* wts = xa  + 8388608;   // 6 * 262144 bf16

  float* outx = (float*)d_out;
  float* ratt = outx + 8388608;

  (void)hipFuncSetAttribute((const void*)k_attn,
                            hipFuncAttributeMaxDynamicSharedMemorySize, 163840);

  k_wt6<<<dim3(1024, 6), dim3(256), 0, stream>>>(wq, wk, wv, wq1, wk1, wfc, wts);

  k_proj<<<dim3(128, 4, 5), dim3(256), 0, stream>>>(
      query, key, value, wts, bq, bk, bv, bq1, bk1, Qh, Kh, Vt, Q1h, K1h);

  k_attn<<<dim3(16, 16), dim3(1024), 163840, stream>>>(
      Qh, Kh, Vt, Q1h, K1h, mask, xa, ratt);

  k_fc<<<dim3(128, 4), dim3(256), 0, stream>>>(
      xa, wts + 5 * 262144, bfc, outx);
}